// Round 1
// baseline (274.261 us; speedup 1.0000x reference)
//
#include <hip/hip_runtime.h>
#include <hip/hip_bf16.h>

#define NN 2048
#define DD 256
#define HD 64
#define LN_EPS 1e-5f

typedef __bf16 bf16x8 __attribute__((ext_vector_type(8)));
typedef __bf16 bf16x4 __attribute__((ext_vector_type(4)));
typedef float  f32x4  __attribute__((ext_vector_type(4)));

static __device__ __forceinline__ bf16x8 make8(bf16x4 lo, bf16x4 hi) {
    return bf16x8{lo[0],lo[1],lo[2],lo[3],hi[0],hi[1],hi[2],hi[3]};
}
// frag: 8 bf16 for one 16x16x32 operand: k-halves at +0 and +16 within a row
static __device__ __forceinline__ bf16x8 ldfrag(const __bf16* p) {
    bf16x4 lo = *(const bf16x4*)p;
    bf16x4 hi = *(const bf16x4*)(p + 16);
    return make8(lo, hi);
}

// ---------------- weight convert + transpose: dst[n][k] = bf16(src[k][n]) ----------
__global__ void wt_kernel(const float* __restrict__ src, __bf16* __restrict__ dst,
                          int K, int N) {
    int i = blockIdx.x * 256 + threadIdx.x;
    if (i < N * K) {
        int n = i / K, k = i - n * K;
        dst[i] = (__bf16)src[k * N + n];
    }
}

// ---------------- generic bf16 MFMA GEMM: C[M,N] = A[M,K] @ Wt[N,K]^T --------------
// EPI: 0 = bf16 out, 1 = rotary(bf16 out, needs pe), 2 = f32 out, 3 = relu bf16 out
template<int EPI, bool ABF>
__global__ __launch_bounds__(256) void gemm_kernel(
    const void* __restrict__ Av, const __bf16* __restrict__ Bt,
    void* __restrict__ Cv, const float* __restrict__ pe,
    int M, int N, int K)
{
    __shared__ alignas(16) __bf16 As[64][36];
    __shared__ alignas(16) __bf16 Bs[64][36];

    const int t = threadIdx.x;
    const int rowbase = blockIdx.y * 64;
    const int colbase = blockIdx.x * 64;
    const int w = t >> 6, lane = t & 63;
    const int wr = w >> 1, wc = w & 1;
    const int lr = lane & 15, lg = lane >> 4;

    const int sr = t >> 2;            // staging row 0..63
    const int scc = (t & 3) * 8;      // staging col chunk

    f32x4 acc[2][2] = {};

    for (int kb = 0; kb < K; kb += 32) {
        __syncthreads();
        // stage A tile (64 x 32)
        {
            long grow = rowbase + sr;
            if (ABF) {
                const __bf16* A = (const __bf16*)Av;
                bf16x8 av = *(const bf16x8*)&A[grow * K + kb + scc];
                *(bf16x4*)&As[sr][scc]     = bf16x4{av[0],av[1],av[2],av[3]};
                *(bf16x4*)&As[sr][scc + 4] = bf16x4{av[4],av[5],av[6],av[7]};
            } else {
                const float* A = (const float*)Av;
                const float4* p = (const float4*)&A[grow * K + kb + scc];
                float4 a0 = p[0], a1 = p[1];
                *(bf16x4*)&As[sr][scc]     = bf16x4{(__bf16)a0.x,(__bf16)a0.y,(__bf16)a0.z,(__bf16)a0.w};
                *(bf16x4*)&As[sr][scc + 4] = bf16x4{(__bf16)a1.x,(__bf16)a1.y,(__bf16)a1.z,(__bf16)a1.w};
            }
        }
        // stage B tile (Wt rows = output cols), 64 x 32
        {
            long gn = colbase + sr;
            bf16x8 bv = *(const bf16x8*)&Bt[gn * K + kb + scc];
            *(bf16x4*)&Bs[sr][scc]     = bf16x4{bv[0],bv[1],bv[2],bv[3]};
            *(bf16x4*)&Bs[sr][scc + 4] = bf16x4{bv[4],bv[5],bv[6],bv[7]};
        }
        __syncthreads();

        bf16x8 af[2], bfr[2];
        #pragma unroll
        for (int mt = 0; mt < 2; ++mt)
            af[mt] = ldfrag(&As[wr*32 + mt*16 + lr][4*lg]);
        #pragma unroll
        for (int nt = 0; nt < 2; ++nt)
            bfr[nt] = ldfrag(&Bs[wc*32 + nt*16 + lr][4*lg]);
        #pragma unroll
        for (int mt = 0; mt < 2; ++mt)
            #pragma unroll
            for (int nt = 0; nt < 2; ++nt)
                acc[mt][nt] = __builtin_amdgcn_mfma_f32_16x16x32_bf16(af[mt], bfr[nt], acc[mt][nt], 0, 0, 0);
    }

    // epilogue: lane holds C[row = 4*lg + r][col = lr] per 16x16 tile
    #pragma unroll
    for (int mt = 0; mt < 2; ++mt) {
        #pragma unroll
        for (int nt = 0; nt < 2; ++nt) {
            #pragma unroll
            for (int r = 0; r < 4; ++r) {
                long grow = rowbase + wr*32 + mt*16 + lg*4 + r;
                int  gcol = colbase + wc*32 + nt*16 + lr;
                float val = acc[mt][nt][r];
                if (EPI == 1) {
                    float partner = __shfl_xor(val, 1);
                    const float* pp = &pe[(grow * DD + gcol) * 2];
                    float c = pp[0], s = pp[1];
                    val = (gcol & 1) ? (val * c + partner * s) : (val * c - partner * s);
                    ((__bf16*)Cv)[grow * N + gcol] = (__bf16)val;
                } else if (EPI == 0) {
                    ((__bf16*)Cv)[grow * N + gcol] = (__bf16)val;
                } else if (EPI == 2) {
                    ((float*)Cv)[grow * N + gcol] = val;
                } else {
                    ((__bf16*)Cv)[grow * N + gcol] = (__bf16)fmaxf(val, 0.f);
                }
            }
        }
    }
}

// ---------------- flash attention: per (b,h), 64 queries/block, SBLK=32 ------------
__global__ __launch_bounds__(256) void attn_kernel(
    const __bf16* __restrict__ q, const __bf16* __restrict__ kk,
    const __bf16* __restrict__ v, __bf16* __restrict__ o)
{
    __shared__ alignas(16) __bf16 Qs[64][68];
    __shared__ alignas(16) __bf16 Ks[32][68];
    __shared__ alignas(16) __bf16 Vt[64][36];   // transposed V, s-col XOR-swizzled
    __shared__ alignas(16) __bf16 Ps[4][16][36];

    const int t = threadIdx.x;
    const int qb = blockIdx.x * 64;
    const int h  = blockIdx.y;
    const int b  = blockIdx.z;
    const int w = t >> 6, lane = t & 63;
    const int lr = lane & 15, lg = lane >> 4;
    const long row0 = (long)b * NN;

    // load Q tile (64 x 64)
    #pragma unroll
    for (int i = 0; i < 2; ++i) {
        int idx = t + i * 256;
        int r = idx >> 3, cc = (idx & 7) * 8;
        bf16x8 qv = *(const bf16x8*)&q[(row0 + qb + r) * DD + h * HD + cc];
        *(bf16x4*)&Qs[r][cc]     = bf16x4{qv[0],qv[1],qv[2],qv[3]};
        *(bf16x4*)&Qs[r][cc + 4] = bf16x4{qv[4],qv[5],qv[6],qv[7]};
    }
    __syncthreads();
    bf16x8 qf[2];
    #pragma unroll
    for (int ks = 0; ks < 2; ++ks)
        qf[ks] = ldfrag(&Qs[w*16 + lr][ks*32 + 4*lg]);

    f32x4 acco[4] = {};
    float mrun[4], lrun[4];
    #pragma unroll
    for (int r = 0; r < 4; ++r) { mrun[r] = -INFINITY; lrun[r] = 0.f; }

    for (int sb = 0; sb < NN; sb += 32) {
        __syncthreads();
        {   // stage K (32 x 64) and V transposed (64 x 32, swizzled)
            int r = t >> 3, cc = (t & 7) * 8;
            bf16x8 kv = *(const bf16x8*)&kk[(row0 + sb + r) * DD + h * HD + cc];
            *(bf16x4*)&Ks[r][cc]     = bf16x4{kv[0],kv[1],kv[2],kv[3]};
            *(bf16x4*)&Ks[r][cc + 4] = bf16x4{kv[4],kv[5],kv[6],kv[7]};
            bf16x8 vv = *(const bf16x8*)&v[(row0 + sb + r) * DD + h * HD + cc];
            #pragma unroll
            for (int j = 0; j < 8; ++j) {
                int hd = cc + j;
                Vt[hd][r ^ (4 * ((hd >> 3) & 7))] = vv[j];
            }
        }
        __syncthreads();

        // scores: Q @ K^T (16q x 32s per wave)
        f32x4 accs[2] = {};
        #pragma unroll
        for (int nt = 0; nt < 2; ++nt)
            #pragma unroll
            for (int ks = 0; ks < 2; ++ks) {
                bf16x8 kf = ldfrag(&Ks[nt*16 + lr][ks*32 + 4*lg]);
                accs[nt] = __builtin_amdgcn_mfma_f32_16x16x32_bf16(qf[ks], kf, accs[nt], 0, 0, 0);
            }

        // online softmax; lane holds rows 4*lg + r, cols {lr, lr+16}
        float sc[4];
        #pragma unroll
        for (int r = 0; r < 4; ++r) {
            float s0 = accs[0][r] * 0.125f, s1 = accs[1][r] * 0.125f;
            float mx = fmaxf(s0, s1);
            #pragma unroll
            for (int m = 1; m < 16; m <<= 1) mx = fmaxf(mx, __shfl_xor(mx, m));
            float mnew = fmaxf(mrun[r], mx);
            float p0 = __expf(s0 - mnew), p1 = __expf(s1 - mnew);
            float rs = p0 + p1;
            #pragma unroll
            for (int m = 1; m < 16; m <<= 1) rs += __shfl_xor(rs, m);
            sc[r] = __expf(mrun[r] - mnew);
            lrun[r] = lrun[r] * sc[r] + rs;
            mrun[r] = mnew;
            Ps[w][lg*4 + r][lr]      = (__bf16)p0;
            Ps[w][lg*4 + r][lr + 16] = (__bf16)p1;
        }
        asm volatile("s_waitcnt lgkmcnt(0)" ::: "memory");
        __builtin_amdgcn_sched_barrier(0);

        bf16x8 pf = ldfrag(&Ps[w][lr][4*lg]);

        // o += P @ V  (V via swizzled transposed LDS)
        #pragma unroll
        for (int nt = 0; nt < 4; ++nt) {
            #pragma unroll
            for (int r = 0; r < 4; ++r) acco[nt][r] *= sc[r];
            int xsw = 4 * (nt*2 + (lr >> 3));
            const __bf16* vrow = &Vt[nt*16 + lr][0];
            bf16x4 lo = *(const bf16x4*)&vrow[(4*lg) ^ xsw];
            bf16x4 hi = *(const bf16x4*)&vrow[(16 + 4*lg) ^ xsw];
            bf16x8 vf = make8(lo, hi);
            acco[nt] = __builtin_amdgcn_mfma_f32_16x16x32_bf16(pf, vf, acco[nt], 0, 0, 0);
        }
    }

    #pragma unroll
    for (int nt = 0; nt < 4; ++nt)
        #pragma unroll
        for (int r = 0; r < 4; ++r) {
            long row = row0 + qb + w*16 + lg*4 + r;
            int  col = h * HD + nt*16 + lr;
            o[row * DD + col] = (__bf16)(acco[nt][r] / lrun[r]);
        }
}

// ---------------- layernorm(m1)*g+b -> cat[:,256:512]; cat[:,0:256] = bf16(x) ------
__global__ __launch_bounds__(256) void ln1_cat_kernel(
    const float* __restrict__ m1, const float* __restrict__ x,
    const float* __restrict__ g, const float* __restrict__ bb,
    __bf16* __restrict__ cat)
{
    __shared__ float red[2][4];
    int row = blockIdx.x, t = threadIdx.x;
    float val = m1[(long)row * DD + t];
    float s = val, sq = val * val;
    #pragma unroll
    for (int m = 1; m < 64; m <<= 1) { s += __shfl_xor(s, m); sq += __shfl_xor(sq, m); }
    int w = t >> 6;
    if ((t & 63) == 0) { red[0][w] = s; red[1][w] = sq; }
    __syncthreads();
    s  = red[0][0] + red[0][1] + red[0][2] + red[0][3];
    sq = red[1][0] + red[1][1] + red[1][2] + red[1][3];
    float mean = s * (1.f / DD);
    float var  = sq * (1.f / DD) - mean * mean;
    float y = (val - mean) * rsqrtf(var + LN_EPS) * g[t] + bb[t];
    cat[(long)row * 512 + 256 + t] = (__bf16)y;
    cat[(long)row * 512 + t]       = (__bf16)x[(long)row * DD + t];
}

// ---------------- out = x + layernorm(m2)*g+b (fp32) -------------------------------
__global__ __launch_bounds__(256) void ln2_res_kernel(
    const float* __restrict__ m2, const float* __restrict__ x,
    const float* __restrict__ g, const float* __restrict__ bb,
    float* __restrict__ out)
{
    __shared__ float red[2][4];
    int row = blockIdx.x, t = threadIdx.x;
    float val = m2[(long)row * DD + t];
    float s = val, sq = val * val;
    #pragma unroll
    for (int m = 1; m < 64; m <<= 1) { s += __shfl_xor(s, m); sq += __shfl_xor(sq, m); }
    int w = t >> 6;
    if ((t & 63) == 0) { red[0][w] = s; red[1][w] = sq; }
    __syncthreads();
    s  = red[0][0] + red[0][1] + red[0][2] + red[0][3];
    sq = red[1][0] + red[1][1] + red[1][2] + red[1][3];
    float mean = s * (1.f / DD);
    float var  = sq * (1.f / DD) - mean * mean;
    float y = (val - mean) * rsqrtf(var + LN_EPS) * g[t] + bb[t];
    out[(long)row * DD + t] = x[(long)row * DD + t] + y;
}

extern "C" void kernel_launch(void* const* d_in, const int* in_sizes, int n_in,
                              void* d_out, int out_size, void* d_ws, size_t ws_size,
                              hipStream_t stream)
{
    const float* x   = (const float*)d_in[0];
    const float* src = (const float*)d_in[1];
    const float* xpe = (const float*)d_in[2];
    const float* spe = (const float*)d_in[3];
    const float* Wq  = (const float*)d_in[4];
    const float* Wk  = (const float*)d_in[5];
    const float* Wv  = (const float*)d_in[6];
    const float* Wm  = (const float*)d_in[7];
    const float* W1  = (const float*)d_in[8];
    const float* W2  = (const float*)d_in[9];
    const float* g1  = (const float*)d_in[10];
    const float* b1  = (const float*)d_in[11];
    const float* g2  = (const float*)d_in[12];
    const float* b2  = (const float*)d_in[13];

    char* ws = (char*)d_ws;
    size_t off = 0;
    auto alloc = [&](size_t bytes) -> void* {
        void* p = ws + off; off += (bytes + 255) & ~(size_t)255; return p;
    };
    __bf16* Wqt = (__bf16*)alloc(256 * 256 * 2);
    __bf16* Wkt = (__bf16*)alloc(256 * 256 * 2);
    __bf16* Wvt = (__bf16*)alloc(256 * 256 * 2);
    __bf16* Wmt = (__bf16*)alloc(256 * 256 * 2);
    __bf16* W1t = (__bf16*)alloc(512 * 512 * 2);
    __bf16* W2t = (__bf16*)alloc(256 * 512 * 2);
    __bf16* qws = (__bf16*)alloc((size_t)4096 * 256 * 2);
    __bf16* kws = (__bf16*)alloc((size_t)4096 * 256 * 2);
    __bf16* vws = (__bf16*)alloc((size_t)4096 * 256 * 2);
    __bf16* ows = (__bf16*)alloc((size_t)4096 * 256 * 2);
    float*  m1  = (float*) alloc((size_t)4096 * 256 * 4);
    __bf16* cat = (__bf16*)alloc((size_t)4096 * 512 * 2);
    __bf16* hws = (__bf16*)alloc((size_t)4096 * 512 * 2);
    float*  m2  = (float*) alloc((size_t)4096 * 256 * 4);

    wt_kernel<<<256, 256, 0, stream>>>(Wq, Wqt, 256, 256);
    wt_kernel<<<256, 256, 0, stream>>>(Wk, Wkt, 256, 256);
    wt_kernel<<<256, 256, 0, stream>>>(Wv, Wvt, 256, 256);
    wt_kernel<<<256, 256, 0, stream>>>(Wm, Wmt, 256, 256);
    wt_kernel<<<1024, 256, 0, stream>>>(W1, W1t, 512, 512);
    wt_kernel<<<512, 256, 0, stream>>>(W2, W2t, 512, 256);

    dim3 g64(4, 64);
    gemm_kernel<1, false><<<g64, 256, 0, stream>>>(x,   Wqt, qws, xpe, 4096, 256, 256);
    gemm_kernel<1, false><<<g64, 256, 0, stream>>>(src, Wkt, kws, spe, 4096, 256, 256);
    gemm_kernel<0, false><<<g64, 256, 0, stream>>>(src, Wvt, vws, nullptr, 4096, 256, 256);

    attn_kernel<<<dim3(32, 4, 2), 256, 0, stream>>>(qws, kws, vws, ows);

    gemm_kernel<2, true><<<g64, 256, 0, stream>>>(ows, Wmt, m1, nullptr, 4096, 256, 256);
    ln1_cat_kernel<<<4096, 256, 0, stream>>>(m1, x, g1, b1, cat);
    gemm_kernel<3, true><<<dim3(8, 64), 256, 0, stream>>>(cat, W1t, hws, nullptr, 4096, 512, 512);
    gemm_kernel<2, true><<<g64, 256, 0, stream>>>(hws, W2t, m2, nullptr, 4096, 256, 512);
    ln2_res_kernel<<<4096, 256, 0, stream>>>(m2, x, g2, b2, (float*)d_out);
}

// Round 8
// 192.418 us; speedup vs baseline: 1.4253x; 1.4253x over previous
//
#include <hip/hip_runtime.h>
#include <hip/hip_bf16.h>

#define NN 2048
#define DD 256
#define HD 64
#define LN_EPS 1e-5f
#define SPLIT 4
#define CHUNK (NN / SPLIT)
#define KVB 64

typedef __bf16 bf16x8 __attribute__((ext_vector_type(8)));
typedef __bf16 bf16x4 __attribute__((ext_vector_type(4)));
typedef float  f32x4  __attribute__((ext_vector_type(4)));

static __device__ __forceinline__ bf16x8 make8(bf16x4 lo, bf16x4 hi) {
    return bf16x8{lo[0],lo[1],lo[2],lo[3],hi[0],hi[1],hi[2],hi[3]};
}
// frag: 8 bf16 for one 16x16x32 operand: k-halves at +0 and +16 within a row
static __device__ __forceinline__ bf16x8 ldfrag(const __bf16* p) {
    bf16x4 lo = *(const bf16x4*)p;
    bf16x4 hi = *(const bf16x4*)(p + 16);
    return make8(lo, hi);
}

// ---------------- all weight transposes in ONE launch ------------------------------
// Wqt[256][256], Wkvt[512][256] (rows 0-255 from Wk, 256-511 from Wv),
// Wmt[256][256], W1t[512][512], W2t[256][512]; dst[n][k] = bf16(src[k][n])
__global__ void wtall_kernel(const float* __restrict__ Wq, const float* __restrict__ Wk,
                             const float* __restrict__ Wv, const float* __restrict__ Wm,
                             const float* __restrict__ W1, const float* __restrict__ W2,
                             __bf16* __restrict__ Wqt, __bf16* __restrict__ Wkvt,
                             __bf16* __restrict__ Wmt, __bf16* __restrict__ W1t,
                             __bf16* __restrict__ W2t)
{
    int i = blockIdx.x * 256 + threadIdx.x;
    if (i < 65536) {
        int n = i >> 8, k = i & 255;
        Wqt[i] = (__bf16)Wq[k * 256 + n];
    } else if (i < 196608) {
        int j = i - 65536;
        int n = j >> 8, k = j & 255;
        Wkvt[j] = (__bf16)(n < 256 ? Wk[k * 256 + n] : Wv[k * 256 + n - 256]);
    } else if (i < 262144) {
        int j = i - 196608;
        int n = j >> 8, k = j & 255;
        Wmt[j] = (__bf16)Wm[k * 256 + n];
    } else if (i < 524288) {
        int j = i - 262144;
        int n = j >> 9, k = j & 511;
        W1t[j] = (__bf16)W1[k * 512 + n];
    } else if (i < 655360) {
        int j = i - 524288;
        int n = j >> 9, k = j & 511;
        W2t[j] = (__bf16)W2[k * 256 + n];
    }
}

// ---------------- generic bf16 MFMA GEMM: C[M,N] = A[M,K] @ Wt[N,K]^T, BK=64 -------
// EPI: 1 = rotary bf16 out, 2 = f32 out, 3 = relu bf16 out,
//      4 = fused kv: cols<256 rotary->Cv, cols>=256 plain->Cv2
template<int EPI, bool ABF>
__global__ __launch_bounds__(256) void gemm_kernel(
    const void* __restrict__ Av, const __bf16* __restrict__ Bt,
    void* __restrict__ Cv, void* __restrict__ Cv2, const float* __restrict__ pe,
    int M, int N, int K)
{
    __shared__ alignas(16) __bf16 As[64][72];
    __shared__ alignas(16) __bf16 Bs[64][72];

    const int t = threadIdx.x;
    const int rowbase = blockIdx.y * 64;
    const int colbase = blockIdx.x * 64;
    const int w = t >> 6, lane = t & 63;
    const int wr = w >> 1, wc = w & 1;
    const int lr = lane & 15, lg = lane >> 4;

    const int sr = t >> 2;            // staging row 0..63
    const int scc = (t & 3) * 16;     // staging col chunk (16 elems)

    f32x4 acc[2][2] = {};

    for (int kb = 0; kb < K; kb += 64) {
        __syncthreads();
        {   // stage A tile (64 x 64)
            long grow = rowbase + sr;
            if (ABF) {
                const __bf16* A = (const __bf16*)Av;
                bf16x8 a0 = *(const bf16x8*)&A[grow * K + kb + scc];
                bf16x8 a1 = *(const bf16x8*)&A[grow * K + kb + scc + 8];
                *(bf16x8*)&As[sr][scc]     = a0;
                *(bf16x8*)&As[sr][scc + 8] = a1;
            } else {
                const float* A = (const float*)Av;
                const float4* p = (const float4*)&A[grow * K + kb + scc];
                float4 a0 = p[0], a1 = p[1], a2 = p[2], a3 = p[3];
                *(bf16x8*)&As[sr][scc] = bf16x8{
                    (__bf16)a0.x,(__bf16)a0.y,(__bf16)a0.z,(__bf16)a0.w,
                    (__bf16)a1.x,(__bf16)a1.y,(__bf16)a1.z,(__bf16)a1.w};
                *(bf16x8*)&As[sr][scc + 8] = bf16x8{
                    (__bf16)a2.x,(__bf16)a2.y,(__bf16)a2.z,(__bf16)a2.w,
                    (__bf16)a3.x,(__bf16)a3.y,(__bf16)a3.z,(__bf16)a3.w};
            }
        }
        {   // stage B tile (Wt rows = output cols), 64 x 64
            long gn = colbase + sr;
            bf16x8 b0 = *(const bf16x8*)&Bt[gn * K + kb + scc];
            bf16x8 b1 = *(const bf16x8*)&Bt[gn * K + kb + scc + 8];
            *(bf16x8*)&Bs[sr][scc]     = b0;
            *(bf16x8*)&Bs[sr][scc + 8] = b1;
        }
        __syncthreads();

        #pragma unroll
        for (int kk = 0; kk < 2; ++kk) {
            bf16x8 af[2], bfr[2];
            #pragma unroll
            for (int mt = 0; mt < 2; ++mt)
                af[mt] = ldfrag(&As[wr*32 + mt*16 + lr][kk*32 + 4*lg]);
            #pragma unroll
            for (int nt = 0; nt < 2; ++nt)
                bfr[nt] = ldfrag(&Bs[wc*32 + nt*16 + lr][kk*32 + 4*lg]);
            #pragma unroll
            for (int mt = 0; mt < 2; ++mt)
                #pragma unroll
                for (int nt = 0; nt < 2; ++nt)
                    acc[mt][nt] = __builtin_amdgcn_mfma_f32_16x16x32_bf16(af[mt], bfr[nt], acc[mt][nt], 0, 0, 0);
        }
    }

    // epilogue: lane holds C[row = 4*lg + r][col = lr] per 16x16 tile
    #pragma unroll
    for (int mt = 0; mt < 2; ++mt) {
        #pragma unroll
        for (int nt = 0; nt < 2; ++nt) {
            #pragma unroll
            for (int r = 0; r < 4; ++r) {
                long grow = rowbase + wr*32 + mt*16 + lg*4 + r;
                int  gcol = colbase + wc*32 + nt*16 + lr;
                float val = acc[mt][nt][r];
                if (EPI == 1) {
                    float partner = __shfl_xor(val, 1);
                    const float* pp = &pe[(grow * DD + gcol) * 2];
                    float c = pp[0], s = pp[1];
                    val = (gcol & 1) ? (val * c + partner * s) : (val * c - partner * s);
                    ((__bf16*)Cv)[grow * N + gcol] = (__bf16)val;
                } else if (EPI == 2) {
                    ((float*)Cv)[grow * N + gcol] = val;
                } else if (EPI == 3) {
                    ((__bf16*)Cv)[grow * N + gcol] = (__bf16)fmaxf(val, 0.f);
                } else { // EPI == 4, block-uniform branch (colbase multiple of 64)
                    if (gcol < 256) {
                        float partner = __shfl_xor(val, 1);
                        const float* pp = &pe[(grow * DD + gcol) * 2];
                        float c = pp[0], s = pp[1];
                        val = (gcol & 1) ? (val * c + partner * s) : (val * c - partner * s);
                        ((__bf16*)Cv)[grow * DD + gcol] = (__bf16)val;
                    } else {
                        ((__bf16*)Cv2)[grow * DD + gcol - 256] = (__bf16)val;
                    }
                }
            }
        }
    }
}

// ---------------- split-KV flash attention partial ---------------------------------
// grid (32 qb, 4 h, 8 = b*SPLIT+sp); each block: 64 q x CHUNK kv, KVB=64 per iter
__global__ __launch_bounds__(256) void attn_part_kernel(
    const __bf16* __restrict__ q, const __bf16* __restrict__ kk,
    const __bf16* __restrict__ v, float* __restrict__ op, float* __restrict__ ml)
{
    __shared__ alignas(16) __bf16 Qs[64][72];
    __shared__ alignas(16) __bf16 Ks[64][72];
    __shared__ alignas(16) __bf16 Vt[64][72];   // transposed V, s-col XOR-swizzled
    __shared__ alignas(16) __bf16 Ps[4][16][72];

    const int t = threadIdx.x;
    const int qb = blockIdx.x * 64;
    const int h  = blockIdx.y;
    const int z  = blockIdx.z;
    const int b  = z >> 2, sp = z & 3;
    const int w = t >> 6, lane = t & 63;
    const int lr = lane & 15, lg = lane >> 4;
    const long row0 = (long)b * NN;

    // load Q tile (64 x 64)
    #pragma unroll
    for (int i = 0; i < 2; ++i) {
        int idx = t + i * 256;
        int r = idx >> 3, cc = (idx & 7) * 8;
        *(bf16x8*)&Qs[r][cc] = *(const bf16x8*)&q[(row0 + qb + r) * DD + h * HD + cc];
    }
    __syncthreads();
    bf16x8 qf[2];
    qf[0] = ldfrag(&Qs[w*16 + lr][4*lg]);
    qf[1] = ldfrag(&Qs[w*16 + lr][32 + 4*lg]);

    f32x4 acco[4] = {};
    float mrun[4], lrun[4];
    #pragma unroll
    for (int r = 0; r < 4; ++r) { mrun[r] = -INFINITY; lrun[r] = 0.f; }

    const int sr = t >> 2, scc = (t & 3) * 16;
    for (int sb = sp * CHUNK; sb < sp * CHUNK + CHUNK; sb += KVB) {
        __syncthreads();
        {   // stage K (64 x 64) and V transposed (swizzled)
            const __bf16* kp = &kk[(row0 + sb + sr) * DD + h * HD + scc];
            *(bf16x8*)&Ks[sr][scc]     = *(const bf16x8*)kp;
            *(bf16x8*)&Ks[sr][scc + 8] = *(const bf16x8*)(kp + 8);
            const __bf16* vp = &v[(row0 + sb + sr) * DD + h * HD + scc];
            bf16x8 v0 = *(const bf16x8*)vp;
            bf16x8 v1 = *(const bf16x8*)(vp + 8);
            #pragma unroll
            for (int j = 0; j < 8; ++j) {
                int hd = scc + j;
                Vt[hd][sr ^ (4 * ((hd >> 3) & 7))] = v0[j];
                int hd2 = scc + 8 + j;
                Vt[hd2][sr ^ (4 * ((hd2 >> 3) & 7))] = v1[j];
            }
        }
        __syncthreads();

        // scores: Q @ K^T (16q x 64s per wave)
        f32x4 accs[4] = {};
        #pragma unroll
        for (int nt = 0; nt < 4; ++nt)
            #pragma unroll
            for (int ks = 0; ks < 2; ++ks) {
                bf16x8 kf = ldfrag(&Ks[nt*16 + lr][ks*32 + 4*lg]);
                accs[nt] = __builtin_amdgcn_mfma_f32_16x16x32_bf16(qf[ks], kf, accs[nt], 0, 0, 0);
            }

        // online softmax; lane holds rows 4*lg + r, cols {lr, lr+16, lr+32, lr+48}
        float sc[4];
        #pragma unroll
        for (int r = 0; r < 4; ++r) {
            float s0 = accs[0][r] * 0.125f, s1 = accs[1][r] * 0.125f;
            float s2 = accs[2][r] * 0.125f, s3 = accs[3][r] * 0.125f;
            float mx = fmaxf(fmaxf(s0, s1), fmaxf(s2, s3));
            #pragma unroll
            for (int m = 1; m < 16; m <<= 1) mx = fmaxf(mx, __shfl_xor(mx, m));
            float mnew = fmaxf(mrun[r], mx);
            float p0 = __expf(s0 - mnew), p1 = __expf(s1 - mnew);
            float p2 = __expf(s2 - mnew), p3 = __expf(s3 - mnew);
            float rs = (p0 + p1) + (p2 + p3);
            #pragma unroll
            for (int m = 1; m < 16; m <<= 1) rs += __shfl_xor(rs, m);
            sc[r] = __expf(mrun[r] - mnew);
            lrun[r] = lrun[r] * sc[r] + rs;
            mrun[r] = mnew;
            Ps[w][lg*4 + r][lr]      = (__bf16)p0;
            Ps[w][lg*4 + r][lr + 16] = (__bf16)p1;
            Ps[w][lg*4 + r][lr + 32] = (__bf16)p2;
            Ps[w][lg*4 + r][lr + 48] = (__bf16)p3;
        }
        asm volatile("s_waitcnt lgkmcnt(0)" ::: "memory");
        __builtin_amdgcn_sched_barrier(0);

        bf16x8 pf[2];
        pf[0] = ldfrag(&Ps[w][lr][4*lg]);
        pf[1] = ldfrag(&Ps[w][lr][32 + 4*lg]);

        // o += P @ V  (V via swizzled transposed LDS)
        #pragma unroll
        for (int nt = 0; nt < 4; ++nt) {
            #pragma unroll
            for (int r = 0; r < 4; ++r) acco[nt][r] *= sc[r];
            int d = nt*16 + lr;
            int xsw = 4 * ((d >> 3) & 7);
            const __bf16* vrow = &Vt[d][0];
            #pragma unroll
            for (int ks = 0; ks < 2; ++ks) {
                bf16x4 lo = *(const bf16x4*)&vrow[(ks*32 + 4*lg) ^ xsw];
                bf16x4 hi = *(const bf16x4*)&vrow[(ks*32 + 16 + 4*lg) ^ xsw];
                acco[nt] = __builtin_amdgcn_mfma_f32_16x16x32_bf16(pf[ks], make8(lo, hi), acco[nt], 0, 0, 0);
            }
        }
    }

    // write unnormalized partial O + (m, l)
    long pr = (long)(sp * 2 + b) * 2048 + qb + w*16 + lg*4;
    #pragma unroll
    for (int nt = 0; nt < 4; ++nt)
        #pragma unroll
        for (int r = 0; r < 4; ++r)
            op[(pr + r) * 256 + h * HD + nt*16 + lr] = acco[nt][r];
    if (lr == 0) {
        #pragma unroll
        for (int r = 0; r < 4; ++r) {
            long mi = ((long)(sp * 2 + b) * 4 + h) * 2048 + (qb + w*16 + lg*4 + r);
            *(float2*)&ml[mi * 2] = make_float2(mrun[r], lrun[r]);
        }
    }
}

// ---------------- combine SPLIT partials -> bf16 O ---------------------------------
__global__ __launch_bounds__(256) void attn_comb_kernel(
    const float* __restrict__ op, const float* __restrict__ ml, __bf16* __restrict__ o)
{
    int row = blockIdx.x;           // b*2048 + n
    int t = threadIdx.x;
    int b = row >> 11, n = row & 2047;
    int h = t >> 6;
    float m[SPLIT], l[SPLIT];
    #pragma unroll
    for (int sp = 0; sp < SPLIT; ++sp) {
        float2 v2 = *(const float2*)&ml[(((long)(sp*2 + b) * 4 + h) * 2048 + n) * 2];
        m[sp] = v2.x; l[sp] = v2.y;
    }
    float M = fmaxf(fmaxf(m[0], m[1]), fmaxf(m[2], m[3]));
    float L = 0.f, oa = 0.f;
    #pragma unroll
    for (int sp = 0; sp < SPLIT; ++sp) {
        float wgt = __expf(m[sp] - M);
        L  += l[sp] * wgt;
        oa += op[((long)(sp*2 + b) * 2048 + n) * 256 + t] * wgt;
    }
    o[(long)row * 256 + t] = (__bf16)(oa / L);
}

// ---------------- layernorm(m1)*g+b -> cat[:,256:512]; cat[:,0:256] = bf16(x) ------
__global__ __launch_bounds__(256) void ln1_cat_kernel(
    const float* __restrict__ m1, const float* __restrict__ x,
    const float* __restrict__ g, const float* __restrict__ bb,
    __bf16* __restrict__ cat)
{
    __shared__ float red[2][4];
    int row = blockIdx.x, t = threadIdx.x;
    float val = m1[(long)row * DD + t];
    float s = val, sq = val * val;
    #pragma unroll
    for (int m = 1; m < 64; m <<= 1) { s += __shfl_xor(s, m); sq += __shfl_xor(sq, m); }
    int w = t >> 6;
    if ((t & 63) == 0) { red[0][w] = s; red[1][w] = sq; }
    __syncthreads();
    s  = red[0][0] + red[0][1] + red[0][2] + red[0][3];
    sq = red[1][0] + red[1][1] + red[1][2] + red[1][3];
    float mean = s * (1.f / DD);
    float var  = sq * (1.f / DD) - mean * mean;
    float y = (val - mean) * rsqrtf(var + LN_EPS) * g[t] + bb[t];
    cat[(long)row * 512 + 256 + t] = (__bf16)y;
    cat[(long)row * 512 + t]       = (__bf16)x[(long)row * DD + t];
}

// ---------------- out = x + layernorm(m2)*g+b (fp32) -------------------------------
__global__ __launch_bounds__(256) void ln2_res_kernel(
    const float* __restrict__ m2, const float* __restrict__ x,
    const float* __restrict__ g, const float* __restrict__ bb,
    float* __restrict__ out)
{
    __shared__ float red[2][4];
    int row = blockIdx.x, t = threadIdx.x;
    float val = m2[(long)row * DD + t];
    float s = val, sq = val * val;
    #pragma unroll
    for (int m = 1; m < 64; m <<= 1) { s += __shfl_xor(s, m); sq += __shfl_xor(sq, m); }
    int w = t >> 6;
    if ((t & 63) == 0) { red[0][w] = s; red[1][w] = sq; }
    __syncthreads();
    s  = red[0][0] + red[0][1] + red[0][2] + red[0][3];
    sq = red[1][0] + red[1][1] + red[1][2] + red[1][3];
    float mean = s * (1.f / DD);
    float var  = sq * (1.f / DD) - mean * mean;
    float y = (val - mean) * rsqrtf(var + LN_EPS) * g[t] + bb[t];
    out[(long)row * DD + t] = x[(long)row * DD + t] + y;
}

extern "C" void kernel_launch(void* const* d_in, const int* in_sizes, int n_in,
                              void* d_out, int out_size, void* d_ws, size_t ws_size,
                              hipStream_t stream)
{
    const float* x   = (const float*)d_in[0];
    const float* src = (const float*)d_in[1];
    const float* xpe = (const float*)d_in[2];
    const float* spe = (const float*)d_in[3];
    const float* Wq  = (const float*)d_in[4];
    const float* Wk  = (const float*)d_in[5];
    const float* Wv  = (const float*)d_in[6];
    const float* Wm  = (const float*)d_in[7];
    const float* W1  = (const float*)d_in[8];
    const float* W2  = (const float*)d_in[9];
    const float* g1  = (const float*)d_in[10];
    const float* b1  = (const float*)d_in[11];
    const float* g2  = (const float*)d_in[12];
    const float* b2  = (const float*)d_in[13];

    char* ws = (char*)d_ws;
    size_t off = 0;
    auto alloc = [&](size_t bytes) -> void* {
        void* p = ws + off; off += (bytes + 255) & ~(size_t)255; return p;
    };
    __bf16* Wqt  = (__bf16*)alloc(256 * 256 * 2);
    __bf16* Wkvt = (__bf16*)alloc(512 * 256 * 2);
    __bf16* Wmt  = (__bf16*)alloc(256 * 256 * 2);
    __bf16* W1t  = (__bf16*)alloc(512 * 512 * 2);
    __bf16* W2t  = (__bf16*)alloc(256 * 512 * 2);
    __bf16* qws  = (__bf16*)alloc((size_t)4096 * 256 * 2);
    __bf16* kws  = (__bf16*)alloc((size_t)4096 * 256 * 2);
    __bf16* vws  = (__bf16*)alloc((size_t)4096 * 256 * 2);
    __bf16* ows  = (__bf16*)alloc((size_t)4096 * 256 * 2);
    // 16 MB region: first holds attention partials (op), later m1/cat/hws/m2
    char*   big  = (char*)alloc((size_t)16 * 1024 * 1024);
    float*  op   = (float*)big;                                  // 4x4096x256 f32
    float*  m1   = (float*)big;                                  // 4 MB
    __bf16* cat  = (__bf16*)(big + (size_t)4  * 1024 * 1024);    // 4 MB
    __bf16* hws  = (__bf16*)(big + (size_t)8  * 1024 * 1024);    // 4 MB
    float*  m2   = (float*)(big + (size_t)12 * 1024 * 1024);     // 4 MB
    float*  ml   = (float*)alloc((size_t)SPLIT * 2 * 4 * 2048 * 2 * 4);

    wtall_kernel<<<2560, 256, 0, stream>>>(Wq, Wk, Wv, Wm, W1, W2,
                                           Wqt, Wkvt, Wmt, W1t, W2t);

    gemm_kernel<1, false><<<dim3(4, 64), 256, 0, stream>>>(x,   Wqt,  qws, nullptr, xpe, 4096, 256, 256);
    gemm_kernel<4, false><<<dim3(8, 64), 256, 0, stream>>>(src, Wkvt, kws, vws,     spe, 4096, 512, 256);

    attn_part_kernel<<<dim3(32, 4, 2 * SPLIT), 256, 0, stream>>>(qws, kws, vws, op, ml);
    attn_comb_kernel<<<4096, 256, 0, stream>>>(op, ml, ows);

    gemm_kernel<2, true><<<dim3(4, 64), 256, 0, stream>>>(ows, Wmt, m1, nullptr, nullptr, 4096, 256, 256);
    ln1_cat_kernel<<<4096, 256, 0, stream>>>(m1, x, g1, b1, cat);
    gemm_kernel<3, true><<<dim3(8, 64), 256, 0, stream>>>(cat, W1t, hws, nullptr, nullptr, 4096, 512, 512);
    gemm_kernel<2, true><<<dim3(4, 64), 256, 0, stream>>>(hws, W2t, m2, nullptr, nullptr, 4096, 256, 512);
    ln2_res_kernel<<<4096, 256, 0, stream>>>(m2, x, g2, b2, (float*)d_out);
}

// Round 10
// 187.577 us; speedup vs baseline: 1.4621x; 1.0258x over previous
//
#include <hip/hip_runtime.h>
#include <hip/hip_bf16.h>

#define NN 2048
#define DD 256
#define HD 64
#define LN_EPS 1e-5f
#define SPLIT 4
#define CHUNK (NN / SPLIT)
#define KVB 64

typedef __bf16 bf16x8 __attribute__((ext_vector_type(8)));
typedef __bf16 bf16x4 __attribute__((ext_vector_type(4)));
typedef float  f32x4  __attribute__((ext_vector_type(4)));

static __device__ __forceinline__ bf16x8 make8(bf16x4 lo, bf16x4 hi) {
    return bf16x8{lo[0],lo[1],lo[2],lo[3],hi[0],hi[1],hi[2],hi[3]};
}
// frag from row-major padded LDS (used for P tiles): k-halves at +0 / +16 elems
static __device__ __forceinline__ bf16x8 ldfrag(const __bf16* p) {
    bf16x4 lo = *(const bf16x4*)p;
    bf16x4 hi = *(const bf16x4*)(p + 16);
    return make8(lo, hi);
}

// ---- async global->LDS stage of a 64x64 bf16 tile -------------------------------
// Linear LDS [64][64] (128B rows). global_load_lds writes lane-linear, so the
// bank swizzle is applied by PRE-SWIZZLING the global source chunk (rule: both
// sides or neither): physical 16B-chunk (r, p) holds logical chunk p^(r&7).
static __device__ __forceinline__ void stage64(const __bf16* __restrict__ g, int ldg,
                                               __bf16* lds, int t) {
    const int w = t >> 6, lane = t & 63;
    #pragma unroll
    for (int i = 0; i < 2; ++i) {
        int chunk = (w + 4*i) * 64 + lane;      // 16B-chunk id 0..511
        int r = chunk >> 3;                     // row 0..63
        int j = (chunk & 7) ^ (r & 7);          // pre-swizzled source chunk
        __builtin_amdgcn_global_load_lds(
            (const __attribute__((address_space(1))) void*)(g + (long)r * ldg + j * 8),
            (__attribute__((address_space(3))) void*)(lds + (w + 4*i) * 512),
            16, 0, 0);
    }
}
// matching swizzled fragment read: byte offset within row XORed with (r&7)<<4
static __device__ __forceinline__ bf16x8 ldfrag_swz(const __bf16* lds, int row, int cbyte) {
    const char* p = (const char*)(lds + row * 64);
    int sw = (row & 7) << 4;
    bf16x4 lo = *(const bf16x4*)(p + (cbyte ^ sw));
    bf16x4 hi = *(const bf16x4*)(p + ((cbyte + 32) ^ sw));
    return make8(lo, hi);
}

// ---------------- prep: weight transposes + bf16 casts of x/source ----------------
// Wqt[256][256], Wkvt[512][256] (K rows 0-255, V rows 256-511), Wmt[256][256],
// W1t[512][512], W2t[256][512]; dst[n][k] = bf16(src[k][n]). xb/srcb = bf16(x/src).
__global__ void wtall_kernel(const float* __restrict__ Wq, const float* __restrict__ Wk,
                             const float* __restrict__ Wv, const float* __restrict__ Wm,
                             const float* __restrict__ W1, const float* __restrict__ W2,
                             const float* __restrict__ x,  const float* __restrict__ src,
                             __bf16* __restrict__ Wqt, __bf16* __restrict__ Wkvt,
                             __bf16* __restrict__ Wmt, __bf16* __restrict__ W1t,
                             __bf16* __restrict__ W2t, __bf16* __restrict__ xb,
                             __bf16* __restrict__ srcb)
{
    int i = blockIdx.x * 256 + threadIdx.x;
    if (i < 65536) {
        int n = i >> 8, k = i & 255;
        Wqt[i] = (__bf16)Wq[k * 256 + n];
    } else if (i < 196608) {
        int j = i - 65536;
        int n = j >> 8, k = j & 255;
        Wkvt[j] = (__bf16)(n < 256 ? Wk[k * 256 + n] : Wv[k * 256 + n - 256]);
    } else if (i < 262144) {
        int j = i - 196608;
        int n = j >> 8, k = j & 255;
        Wmt[j] = (__bf16)Wm[k * 256 + n];
    } else if (i < 524288) {
        int j = i - 262144;
        int n = j >> 9, k = j & 511;
        W1t[j] = (__bf16)W1[k * 512 + n];
    } else if (i < 655360) {
        int j = i - 524288;
        int n = j >> 9, k = j & 511;
        W2t[j] = (__bf16)W2[k * 256 + n];
    } else if (i < 786432) {            // x -> xb, 8 elems per job
        int j = i - 655360;
        const float4* p = (const float4*)&x[(long)j * 8];
        float4 a0 = p[0], a1 = p[1];
        *(bf16x8*)&xb[(long)j * 8] = bf16x8{
            (__bf16)a0.x,(__bf16)a0.y,(__bf16)a0.z,(__bf16)a0.w,
            (__bf16)a1.x,(__bf16)a1.y,(__bf16)a1.z,(__bf16)a1.w};
    } else if (i < 917504) {            // source -> srcb
        int j = i - 786432;
        const float4* p = (const float4*)&src[(long)j * 8];
        float4 a0 = p[0], a1 = p[1];
        *(bf16x8*)&srcb[(long)j * 8] = bf16x8{
            (__bf16)a0.x,(__bf16)a0.y,(__bf16)a0.z,(__bf16)a0.w,
            (__bf16)a1.x,(__bf16)a1.y,(__bf16)a1.z,(__bf16)a1.w};
    }
}

// ---------------- bf16 MFMA GEMM v2: gload_lds staging, BK=64 ----------------------
// EPI: 2 = f32 out C1, 3 = relu bf16 out C1,
//      5 = fused QKV: blocks x<4 -> Q proj (A1,B1,pe1)->C1 rotary;
//                     blocks x>=4 -> KV proj (A2,B2,pe2): col<256 rotary->C2, else->C3
template<int EPI>
__global__ __launch_bounds__(256) void gemm2_kernel(
    const __bf16* __restrict__ A1, const __bf16* __restrict__ A2,
    const __bf16* __restrict__ B1, const __bf16* __restrict__ B2,
    void* __restrict__ C1, void* __restrict__ C2, void* __restrict__ C3,
    const float* __restrict__ pe1, const float* __restrict__ pe2,
    int M, int N, int K)
{
    __shared__ alignas(16) __bf16 As[64 * 64];
    __shared__ alignas(16) __bf16 Bs[64 * 64];

    const int t = threadIdx.x;
    const int rowbase = blockIdx.y * 64;
    const int w = t >> 6, lane = t & 63;
    const int wr = w >> 1, wc = w & 1;
    const int lr = lane & 15, lg = lane >> 4;

    const __bf16* Ap = A1;
    const __bf16* Bp = B1;
    const float*  pe = pe1;
    int colbase = blockIdx.x * 64;
    bool isQ = true;
    if (EPI == 5) {
        isQ = blockIdx.x < 4;
        if (!isQ) { Ap = A2; Bp = B2; pe = pe2; colbase = (blockIdx.x - 4) * 64; }
    }

    f32x4 acc[2][2] = {};

    for (int kb = 0; kb < K; kb += 64) {
        __syncthreads();
        stage64(Ap + (long)rowbase * K + kb, K, As, t);
        stage64(Bp + (long)colbase * K + kb, K, Bs, t);
        __syncthreads();

        #pragma unroll
        for (int kk = 0; kk < 2; ++kk) {
            bf16x8 af[2], bfr[2];
            #pragma unroll
            for (int mt = 0; mt < 2; ++mt)
                af[mt] = ldfrag_swz(As, wr*32 + mt*16 + lr, kk*64 + lg*8);
            #pragma unroll
            for (int nt = 0; nt < 2; ++nt)
                bfr[nt] = ldfrag_swz(Bs, wc*32 + nt*16 + lr, kk*64 + lg*8);
            #pragma unroll
            for (int mt = 0; mt < 2; ++mt)
                #pragma unroll
                for (int nt = 0; nt < 2; ++nt)
                    acc[mt][nt] = __builtin_amdgcn_mfma_f32_16x16x32_bf16(af[mt], bfr[nt], acc[mt][nt], 0, 0, 0);
        }
    }

    // epilogue: lane holds C[row = 4*lg + r][col = lr] per 16x16 tile
    #pragma unroll
    for (int mt = 0; mt < 2; ++mt) {
        #pragma unroll
        for (int nt = 0; nt < 2; ++nt) {
            #pragma unroll
            for (int r = 0; r < 4; ++r) {
                long grow = rowbase + wr*32 + mt*16 + lg*4 + r;
                int  gcol = colbase + wc*32 + nt*16 + lr;
                float val = acc[mt][nt][r];
                if (EPI == 2) {
                    ((float*)C1)[grow * N + gcol] = val;
                } else if (EPI == 3) {
                    ((__bf16*)C1)[grow * N + gcol] = (__bf16)fmaxf(val, 0.f);
                } else {  // EPI == 5; branches block-uniform (colbase mult of 64)
                    if (isQ || gcol < 256) {
                        float partner = __shfl_xor(val, 1);
                        const float* pp = &pe[(grow * DD + gcol) * 2];
                        float c = pp[0], s = pp[1];
                        val = (gcol & 1) ? (val * c + partner * s) : (val * c - partner * s);
                        ((__bf16*)(isQ ? C1 : C2))[grow * DD + gcol] = (__bf16)val;
                    } else {
                        ((__bf16*)C3)[grow * DD + gcol - 256] = (__bf16)val;
                    }
                }
            }
        }
    }
}

// ---------------- split-KV flash attention partial ---------------------------------
// grid (32 qb, 4 h, 8 = b*SPLIT+sp); each block: 64 q x CHUNK kv, KVB=64 per iter
__global__ __launch_bounds__(256) void attn_part_kernel(
    const __bf16* __restrict__ q, const __bf16* __restrict__ kk,
    const __bf16* __restrict__ v, float* __restrict__ op, float* __restrict__ ml)
{
    __shared__ alignas(16) __bf16 Qs[64 * 64];   // linear, swizzled (stage64)
    __shared__ alignas(16) __bf16 Ks[64 * 64];   // linear, swizzled (stage64)
    __shared__ alignas(16) __bf16 Vt[64][72];    // transposed V, s-col XOR-swizzled
    __shared__ alignas(16) __bf16 Ps[4][16][72];

    const int t = threadIdx.x;
    const int qb = blockIdx.x * 64;
    const int h  = blockIdx.y;
    const int z  = blockIdx.z;
    const int b  = z >> 2, sp = z & 3;
    const int w = t >> 6, lane = t & 63;
    const int lr = lane & 15, lg = lane >> 4;
    const long row0 = (long)b * NN;

    // load Q tile (64 x 64) via gload_lds
    stage64(q + (row0 + qb) * DD + h * HD, DD, Qs, t);
    __syncthreads();
    bf16x8 qf[2];
    qf[0] = ldfrag_swz(Qs, w*16 + lr, lg*8);
    qf[1] = ldfrag_swz(Qs, w*16 + lr, 64 + lg*8);

    f32x4 acco[4] = {};
    float mrun[4], lrun[4];
    #pragma unroll
    for (int r = 0; r < 4; ++r) { mrun[r] = -INFINITY; lrun[r] = 0.f; }

    const int sr = t >> 2, scc = (t & 3) * 16;
    for (int sb = sp * CHUNK; sb < sp * CHUNK + CHUNK; sb += KVB) {
        __syncthreads();
        // stage K via gload_lds; V transposed via VGPR scatter
        stage64(kk + (row0 + sb) * DD + h * HD, DD, Ks, t);
        {
            const __bf16* vp = &v[(row0 + sb + sr) * DD + h * HD + scc];
            bf16x8 v0 = *(const bf16x8*)vp;
            bf16x8 v1 = *(const bf16x8*)(vp + 8);
            #pragma unroll
            for (int j = 0; j < 8; ++j) {
                int hd = scc + j;
                Vt[hd][sr ^ (4 * ((hd >> 3) & 7))] = v0[j];
                int hd2 = scc + 8 + j;
                Vt[hd2][sr ^ (4 * ((hd2 >> 3) & 7))] = v1[j];
            }
        }
        __syncthreads();

        // scores: Q @ K^T (16q x 64s per wave)
        f32x4 accs[4] = {};
        #pragma unroll
        for (int nt = 0; nt < 4; ++nt)
            #pragma unroll
            for (int ks = 0; ks < 2; ++ks) {
                bf16x8 kf = ldfrag_swz(Ks, nt*16 + lr, ks*64 + lg*8);
                accs[nt] = __builtin_amdgcn_mfma_f32_16x16x32_bf16(qf[ks], kf, accs[nt], 0, 0, 0);
            }

        // online softmax; lane holds rows 4*lg + r, cols {lr, lr+16, lr+32, lr+48}
        float sc[4];
        #pragma unroll
        for (int r = 0; r < 4; ++r) {
            float s0 = accs[0][r] * 0.125f, s1 = accs[1][r] * 0.125f;
            float s2 = accs[2][r] * 0.125f, s3 = accs[3][r] * 0.125f;
            float mx = fmaxf(fmaxf(s0, s1), fmaxf(s2, s3));
            #pragma unroll
            for (int m = 1; m < 16; m <<= 1) mx = fmaxf(mx, __shfl_xor(mx, m));
            float mnew = fmaxf(mrun[r], mx);
            float p0 = __expf(s0 - mnew), p1 = __expf(s1 - mnew);
            float p2 = __expf(s2 - mnew), p3 = __expf(s3 - mnew);
            float rs = (p0 + p1) + (p2 + p3);
            #pragma unroll
            for (int m = 1; m < 16; m <<= 1) rs += __shfl_xor(rs, m);
            sc[r] = __expf(mrun[r] - mnew);
            lrun[r] = lrun[r] * sc[r] + rs;
            mrun[r] = mnew;
            Ps[w][lg*4 + r][lr]      = (__bf16)p0;
            Ps[w][lg*4 + r][lr + 16] = (__bf16)p1;
            Ps[w][lg*4 + r][lr + 32] = (__bf16)p2;
            Ps[w][lg*4 + r][lr + 48] = (__bf16)p3;
        }
        asm volatile("s_waitcnt lgkmcnt(0)" ::: "memory");
        __builtin_amdgcn_sched_barrier(0);

        bf16x8 pf[2];
        pf[0] = ldfrag(&Ps[w][lr][4*lg]);
        pf[1] = ldfrag(&Ps[w][lr][32 + 4*lg]);

        // o += P @ V  (V via swizzled transposed LDS)
        #pragma unroll
        for (int nt = 0; nt < 4; ++nt) {
            #pragma unroll
            for (int r = 0; r < 4; ++r) acco[nt][r] *= sc[r];
            int d = nt*16 + lr;
            int xsw = 4 * ((d >> 3) & 7);
            const __bf16* vrow = &Vt[d][0];
            #pragma unroll
            for (int ks = 0; ks < 2; ++ks) {
                bf16x4 lo = *(const bf16x4*)&vrow[(ks*32 + 4*lg) ^ xsw];
                bf16x4 hi = *(const bf16x4*)&vrow[(ks*32 + 16 + 4*lg) ^ xsw];
                acco[nt] = __builtin_amdgcn_mfma_f32_16x16x32_bf16(pf[ks], make8(lo, hi), acco[nt], 0, 0, 0);
            }
        }
    }

    // write unnormalized partial O + (m, l)
    long pr = (long)(sp * 2 + b) * 2048 + qb + w*16 + lg*4;
    #pragma unroll
    for (int nt = 0; nt < 4; ++nt)
        #pragma unroll
        for (int r = 0; r < 4; ++r)
            op[(pr + r) * 256 + h * HD + nt*16 + lr] = acco[nt][r];
    if (lr == 0) {
        #pragma unroll
        for (int r = 0; r < 4; ++r) {
            long mi = ((long)(sp * 2 + b) * 4 + h) * 2048 + (qb + w*16 + lg*4 + r);
            *(float2*)&ml[mi * 2] = make_float2(mrun[r], lrun[r]);
        }
    }
}

// ---------------- combine SPLIT partials -> bf16 O ---------------------------------
__global__ __launch_bounds__(256) void attn_comb_kernel(
    const float* __restrict__ op, const float* __restrict__ ml, __bf16* __restrict__ o)
{
    int row = blockIdx.x;           // b*2048 + n
    int t = threadIdx.x;
    int b = row >> 11, n = row & 2047;
    int h = t >> 6;
    float m[SPLIT], l[SPLIT];
    #pragma unroll
    for (int sp = 0; sp < SPLIT; ++sp) {
        float2 v2 = *(const float2*)&ml[(((long)(sp*2 + b) * 4 + h) * 2048 + n) * 2];
        m[sp] = v2.x; l[sp] = v2.y;
    }
    float M = fmaxf(fmaxf(m[0], m[1]), fmaxf(m[2], m[3]));
    float L = 0.f, oa = 0.f;
    #pragma unroll
    for (int sp = 0; sp < SPLIT; ++sp) {
        float wgt = __expf(m[sp] - M);
        L  += l[sp] * wgt;
        oa += op[((long)(sp*2 + b) * 2048 + n) * 256 + t] * wgt;
    }
    o[(long)row * 256 + t] = (__bf16)(oa / L);
}

// ---------------- layernorm(m1)*g+b -> cat[:,256:512]; cat[:,0:256] = bf16(x) ------
__global__ __launch_bounds__(256) void ln1_cat_kernel(
    const float* __restrict__ m1, const float* __restrict__ x,
    const float* __restrict__ g, const float* __restrict__ bb,
    __bf16* __restrict__ cat)
{
    __shared__ float red[2][4];
    int row = blockIdx.x, t = threadIdx.x;
    float val = m1[(long)row * DD + t];
    float s = val, sq = val * val;
    #pragma unroll
    for (int m = 1; m < 64; m <<= 1) { s += __shfl_xor(s, m); sq += __shfl_xor(sq, m); }
    int w = t >> 6;
    if ((t & 63) == 0) { red[0][w] = s; red[1][w] = sq; }
    __syncthreads();
    s  = red[0][0] + red[0][1] + red[0][2] + red[0][3];
    sq = red[1][0] + red[1][1] + red[1][2] + red[1][3];
    float mean = s * (1.f / DD);
    float var  = sq * (1.f / DD) - mean * mean;
    float y = (val - mean) * rsqrtf(var + LN_EPS) * g[t] + bb[t];
    cat[(long)row * 512 + 256 + t] = (__bf16)y;
    cat[(long)row * 512 + t]       = (__bf16)x[(long)row * DD + t];
}

// ---------------- out = x + layernorm(m2)*g+b (fp32) -------------------------------
__global__ __launch_bounds__(256) void ln2_res_kernel(
    const float* __restrict__ m2, const float* __restrict__ x,
    const float* __restrict__ g, const float* __restrict__ bb,
    float* __restrict__ out)
{
    __shared__ float red[2][4];
    int row = blockIdx.x, t = threadIdx.x;
    float val = m2[(long)row * DD + t];
    float s = val, sq = val * val;
    #pragma unroll
    for (int m = 1; m < 64; m <<= 1) { s += __shfl_xor(s, m); sq += __shfl_xor(sq, m); }
    int w = t >> 6;
    if ((t & 63) == 0) { red[0][w] = s; red[1][w] = sq; }
    __syncthreads();
    s  = red[0][0] + red[0][1] + red[0][2] + red[0][3];
    sq = red[1][0] + red[1][1] + red[1][2] + red[1][3];
    float mean = s * (1.f / DD);
    float var  = sq * (1.f / DD) - mean * mean;
    float y = (val - mean) * rsqrtf(var + LN_EPS) * g[t] + bb[t];
    out[(long)row * DD + t] = x[(long)row * DD + t] + y;
}

extern "C" void kernel_launch(void* const* d_in, const int* in_sizes, int n_in,
                              void* d_out, int out_size, void* d_ws, size_t ws_size,
                              hipStream_t stream)
{
    const float* x   = (const float*)d_in[0];
    const float* src = (const float*)d_in[1];
    const float* xpe = (const float*)d_in[2];
    const float* spe = (const float*)d_in[3];
    const float* Wq  = (const float*)d_in[4];
    const float* Wk  = (const float*)d_in[5];
    const float* Wv  = (const float*)d_in[6];
    const float* Wm  = (const float*)d_in[7];
    const float* W1  = (const float*)d_in[8];
    const float* W2  = (const float*)d_in[9];
    const float* g1  = (const float*)d_in[10];
    const float* b1  = (const float*)d_in[11];
    const float* g2  = (const float*)d_in[12];
    const float* b2  = (const float*)d_in[13];

    char* ws = (char*)d_ws;
    size_t off = 0;
    auto alloc = [&](size_t bytes) -> void* {
        void* p = ws + off; off += (bytes + 255) & ~(size_t)255; return p;
    };
    __bf16* Wqt  = (__bf16*)alloc(256 * 256 * 2);
    __bf16* Wkvt = (__bf16*)alloc(512 * 256 * 2);
    __bf16* Wmt  = (__bf16*)alloc(256 * 256 * 2);
    __bf16* W1t  = (__bf16*)alloc(512 * 512 * 2);
    __bf16* W2t  = (__bf16*)alloc(256 * 512 * 2);
    __bf16* xb   = (__bf16*)alloc((size_t)4096 * 256 * 2);
    __bf16* srcb = (__bf16*)alloc((size_t)4096 * 256 * 2);
    __bf16* qws  = (__bf16*)alloc((size_t)4096 * 256 * 2);
    __bf16* kws  = (__bf16*)alloc((size_t)4096 * 256 * 2);
    __bf16* vws  = (__bf16*)alloc((size_t)4096 * 256 * 2);
    __bf16* ows  = (__bf16*)alloc((size_t)4096 * 256 * 2);
    // 16 MB region: first holds attention partials (op), later m1/cat/hws/m2
    char*   big  = (char*)alloc((size_t)16 * 1024 * 1024);
    float*  op   = (float*)big;                                  // 4x4096x256 f32
    float*  m1   = (float*)big;                                  // 4 MB
    __bf16* cat  = (__bf16*)(big + (size_t)4  * 1024 * 1024);    // 4 MB
    __bf16* hws  = (__bf16*)(big + (size_t)8  * 1024 * 1024);    // 4 MB
    float*  m2   = (float*)(big + (size_t)12 * 1024 * 1024);     // 4 MB
    float*  ml   = (float*)alloc((size_t)SPLIT * 2 * 4 * 2048 * 2 * 4);

    wtall_kernel<<<3584, 256, 0, stream>>>(Wq, Wk, Wv, Wm, W1, W2, x, src,
                                           Wqt, Wkvt, Wmt, W1t, W2t, xb, srcb);

    // fused Q + KV projections (one dispatch, 768 blocks)
    gemm2_kernel<5><<<dim3(12, 64), 256, 0, stream>>>(
        xb, srcb, Wqt, Wkvt, qws, kws, vws, xpe, spe, 4096, 256, 256);

    attn_part_kernel<<<dim3(32, 4, 2 * SPLIT), 256, 0, stream>>>(qws, kws, vws, op, ml);
    attn_comb_kernel<<<4096, 256, 0, stream>>>(op, ml, ows);

    gemm2_kernel<2><<<dim3(4, 64), 256, 0, stream>>>(
        ows, nullptr, Wmt, nullptr, m1, nullptr, nullptr, nullptr, nullptr, 4096, 256, 256);
    ln1_cat_kernel<<<4096, 256, 0, stream>>>(m1, x, g1, b1, cat);
    gemm2_kernel<3><<<dim3(8, 64), 256, 0, stream>>>(
        cat, nullptr, W1t, nullptr, hws, nullptr, nullptr, nullptr, nullptr, 4096, 512, 512);
    gemm2_kernel<2><<<dim3(4, 64), 256, 0, stream>>>(
        hws, nullptr, W2t, nullptr, m2, nullptr, nullptr, nullptr, nullptr, 4096, 256, 512);
    ln2_res_kernel<<<4096, 256, 0, stream>>>(m2, x, g2, b2, (float*)d_out);
}

// Round 12
// 182.839 us; speedup vs baseline: 1.5000x; 1.0259x over previous
//
#include <hip/hip_runtime.h>
#include <hip/hip_bf16.h>

#define NN 2048
#define DD 256
#define HD 64
#define LN_EPS 1e-5f
#define SPLIT 8
#define CHUNK (NN / SPLIT)
#define KVB 64

typedef __bf16 bf16x8 __attribute__((ext_vector_type(8)));
typedef __bf16 bf16x4 __attribute__((ext_vector_type(4)));
typedef float  f32x4  __attribute__((ext_vector_type(4)));

static __device__ __forceinline__ bf16x8 make8(bf16x4 lo, bf16x4 hi) {
    return bf16x8{lo[0],lo[1],lo[2],lo[3],hi[0],hi[1],hi[2],hi[3]};
}
// frag from row-major padded LDS (P tiles): k-halves at +0 / +16 elems
static __device__ __forceinline__ bf16x8 ldfrag(const __bf16* p) {
    bf16x4 lo = *(const bf16x4*)p;
    bf16x4 hi = *(const bf16x4*)(p + 16);
    return make8(lo, hi);
}

// ---- async global->LDS stage of a 64x64 bf16 tile (linear LDS, pre-swizzled src) --
static __device__ __forceinline__ void stage64(const __bf16* __restrict__ g, int ldg,
                                               __bf16* lds, int t) {
    const int w = t >> 6, lane = t & 63;
    #pragma unroll
    for (int i = 0; i < 2; ++i) {
        int chunk = (w + 4*i) * 64 + lane;      // 16B-chunk id 0..511
        int r = chunk >> 3;                     // row 0..63
        int j = (chunk & 7) ^ (r & 7);          // pre-swizzled source chunk
        __builtin_amdgcn_global_load_lds(
            (const __attribute__((address_space(1))) void*)(g + (long)r * ldg + j * 8),
            (__attribute__((address_space(3))) void*)(lds + (w + 4*i) * 512),
            16, 0, 0);
    }
}
// matching swizzled fragment read: byte offset within row XORed with (r&7)<<4
static __device__ __forceinline__ bf16x8 ldfrag_swz(const __bf16* lds, int row, int cbyte) {
    const char* p = (const char*)(lds + row * 64);
    int sw = (row & 7) << 4;
    bf16x4 lo = *(const bf16x4*)(p + (cbyte ^ sw));
    bf16x4 hi = *(const bf16x4*)(p + ((cbyte + 32) ^ sw));
    return make8(lo, hi);
}

// ---------------- prep: weight transposes + bf16 casts of x/source ----------------
__global__ void wtall_kernel(const float* __restrict__ Wq, const float* __restrict__ Wk,
                             const float* __restrict__ Wv, const float* __restrict__ Wm,
                             const float* __restrict__ W1, const float* __restrict__ W2,
                             const float* __restrict__ x,  const float* __restrict__ src,
                             __bf16* __restrict__ Wqt, __bf16* __restrict__ Wkvt,
                             __bf16* __restrict__ Wmt, __bf16* __restrict__ W1t,
                             __bf16* __restrict__ W2t, __bf16* __restrict__ xb,
                             __bf16* __restrict__ srcb)
{
    int i = blockIdx.x * 256 + threadIdx.x;
    if (i < 65536) {
        int n = i >> 8, k = i & 255;
        Wqt[i] = (__bf16)Wq[k * 256 + n];
    } else if (i < 196608) {
        int j = i - 65536;
        int n = j >> 8, k = j & 255;
        Wkvt[j] = (__bf16)(n < 256 ? Wk[k * 256 + n] : Wv[k * 256 + n - 256]);
    } else if (i < 262144) {
        int j = i - 196608;
        int n = j >> 8, k = j & 255;
        Wmt[j] = (__bf16)Wm[k * 256 + n];
    } else if (i < 524288) {
        int j = i - 262144;
        int n = j >> 9, k = j & 511;
        W1t[j] = (__bf16)W1[k * 512 + n];
    } else if (i < 655360) {
        int j = i - 524288;
        int n = j >> 9, k = j & 511;
        W2t[j] = (__bf16)W2[k * 256 + n];
    } else if (i < 786432) {            // x -> xb
        int j = i - 655360;
        const float4* p = (const float4*)&x[(long)j * 8];
        float4 a0 = p[0], a1 = p[1];
        *(bf16x8*)&xb[(long)j * 8] = bf16x8{
            (__bf16)a0.x,(__bf16)a0.y,(__bf16)a0.z,(__bf16)a0.w,
            (__bf16)a1.x,(__bf16)a1.y,(__bf16)a1.z,(__bf16)a1.w};
    } else if (i < 917504) {            // source -> srcb
        int j = i - 786432;
        const float4* p = (const float4*)&src[(long)j * 8];
        float4 a0 = p[0], a1 = p[1];
        *(bf16x8*)&srcb[(long)j * 8] = bf16x8{
            (__bf16)a0.x,(__bf16)a0.y,(__bf16)a0.z,(__bf16)a0.w,
            (__bf16)a1.x,(__bf16)a1.y,(__bf16)a1.z,(__bf16)a1.w};
    }
}

// ---------------- bf16 MFMA GEMM: 64x64 tile, gload_lds staging, BK=64 -------------
// EPI: 3 = relu bf16 out C1,
//      5 = fused QKV: blocks x<4 -> Q proj (A1,B1,pe1)->C1 rotary;
//                     blocks x>=4 -> KV proj (A2,B2,pe2): col<256 rotary->C2, else->C3
template<int EPI>
__global__ __launch_bounds__(256) void gemm2_kernel(
    const __bf16* __restrict__ A1, const __bf16* __restrict__ A2,
    const __bf16* __restrict__ B1, const __bf16* __restrict__ B2,
    void* __restrict__ C1, void* __restrict__ C2, void* __restrict__ C3,
    const float* __restrict__ pe1, const float* __restrict__ pe2,
    int M, int N, int K)
{
    __shared__ alignas(16) __bf16 As[64 * 64];
    __shared__ alignas(16) __bf16 Bs[64 * 64];

    const int t = threadIdx.x;
    const int rowbase = blockIdx.y * 64;
    const int w = t >> 6, lane = t & 63;
    const int wr = w >> 1, wc = w & 1;
    const int lr = lane & 15, lg = lane >> 4;

    const __bf16* Ap = A1;
    const __bf16* Bp = B1;
    const float*  pe = pe1;
    int colbase = blockIdx.x * 64;
    bool isQ = true;
    if (EPI == 5) {
        isQ = blockIdx.x < 4;
        if (!isQ) { Ap = A2; Bp = B2; pe = pe2; colbase = (blockIdx.x - 4) * 64; }
    }

    f32x4 acc[2][2] = {};

    for (int kb = 0; kb < K; kb += 64) {
        __syncthreads();
        stage64(Ap + (long)rowbase * K + kb, K, As, t);
        stage64(Bp + (long)colbase * K + kb, K, Bs, t);
        __syncthreads();

        #pragma unroll
        for (int kk = 0; kk < 2; ++kk) {
            bf16x8 af[2], bfr[2];
            #pragma unroll
            for (int mt = 0; mt < 2; ++mt)
                af[mt] = ldfrag_swz(As, wr*32 + mt*16 + lr, kk*64 + lg*8);
            #pragma unroll
            for (int nt = 0; nt < 2; ++nt)
                bfr[nt] = ldfrag_swz(Bs, wc*32 + nt*16 + lr, kk*64 + lg*8);
            #pragma unroll
            for (int mt = 0; mt < 2; ++mt)
                #pragma unroll
                for (int nt = 0; nt < 2; ++nt)
                    acc[mt][nt] = __builtin_amdgcn_mfma_f32_16x16x32_bf16(af[mt], bfr[nt], acc[mt][nt], 0, 0, 0);
        }
    }

    // epilogue: lane holds C[row = 4*lg + r][col = lr] per 16x16 tile
    #pragma unroll
    for (int mt = 0; mt < 2; ++mt) {
        #pragma unroll
        for (int nt = 0; nt < 2; ++nt) {
            #pragma unroll
            for (int r = 0; r < 4; ++r) {
                long grow = rowbase + wr*32 + mt*16 + lg*4 + r;
                int  gcol = colbase + wc*32 + nt*16 + lr;
                float val = acc[mt][nt][r];
                if (EPI == 3) {
                    ((__bf16*)C1)[grow * N + gcol] = (__bf16)fmaxf(val, 0.f);
                } else {  // EPI == 5; branches block-uniform
                    if (isQ || gcol < 256) {
                        float partner = __shfl_xor(val, 1);
                        const float* pp = &pe[(grow * DD + gcol) * 2];
                        float c = pp[0], s = pp[1];
                        val = (gcol & 1) ? (val * c + partner * s) : (val * c - partner * s);
                        ((__bf16*)(isQ ? C1 : C2))[grow * DD + gcol] = (__bf16)val;
                    } else {
                        ((__bf16*)C3)[grow * DD + gcol - 256] = (__bf16)val;
                    }
                }
            }
        }
    }
}

// ---------------- fused row-wide GEMM + LayerNorm epilogue -------------------------
// Block: 16 rows x 256 cols (full row width). MODE 0: cat build (Wm + ln1 + x-copy);
// MODE 1: out = xf + LN(A@Bt^T) (W2 + ln2 + residual). Grid = M/16 = 256 blocks.
template<int MODE>
__global__ __launch_bounds__(256) void gemm_ln_kernel(
    const __bf16* __restrict__ A, const __bf16* __restrict__ Bt,
    const __bf16* __restrict__ xb, const float* __restrict__ xf,
    const float* __restrict__ g, const float* __restrict__ bb,
    void* __restrict__ out, int K)
{
    __shared__ alignas(16) __bf16 As[16 * 64];
    __shared__ alignas(16) __bf16 Bs[256 * 64];
    __shared__ float red[2][4][16];

    const int t = threadIdx.x;
    const int w = t >> 6, lane = t & 63;
    const int lr = lane & 15, lg = lane >> 4;
    const int rowbase = blockIdx.x * 16;

    f32x4 acc[4] = {};
    for (int kb = 0; kb < K; kb += 64) {
        __syncthreads();
        if (w < 2) {   // stage A (16x64): 128 chunks, waves 0-1
            int c = w * 64 + lane;
            int r = c >> 3, j = (c & 7) ^ (r & 7);
            __builtin_amdgcn_global_load_lds(
                (const __attribute__((address_space(1))) void*)(A + (long)(rowbase + r) * K + kb + j * 8),
                (__attribute__((address_space(3))) void*)(As + w * 512),
                16, 0, 0);
        }
        #pragma unroll
        for (int i = 0; i < 8; ++i) {  // stage B (256x64): 2048 chunks
            int c = (w + 4 * i) * 64 + lane;
            int r = c >> 3, j = (c & 7) ^ (r & 7);
            __builtin_amdgcn_global_load_lds(
                (const __attribute__((address_space(1))) void*)(Bt + (long)r * K + kb + j * 8),
                (__attribute__((address_space(3))) void*)(Bs + (w + 4 * i) * 512),
                16, 0, 0);
        }
        __syncthreads();
        #pragma unroll
        for (int kk = 0; kk < 2; ++kk) {
            bf16x8 af = ldfrag_swz(As, lr, kk*64 + lg*8);
            #pragma unroll
            for (int nt = 0; nt < 4; ++nt) {
                bf16x8 bf = ldfrag_swz(Bs, w*64 + nt*16 + lr, kk*64 + lg*8);
                acc[nt] = __builtin_amdgcn_mfma_f32_16x16x32_bf16(af, bf, acc[nt], 0, 0, 0);
            }
        }
    }

    // lane holds C[row = 4lg + r][col = w*64 + nt*16 + lr]; LN over 256 cols/row
    #pragma unroll
    for (int r = 0; r < 4; ++r) {
        float s = 0.f, q = 0.f;
        #pragma unroll
        for (int nt = 0; nt < 4; ++nt) { float v_ = acc[nt][r]; s += v_; q += v_ * v_; }
        #pragma unroll
        for (int m = 1; m < 16; m <<= 1) { s += __shfl_xor(s, m); q += __shfl_xor(q, m); }
        if (lr == 0) { red[0][w][lg*4 + r] = s; red[1][w][lg*4 + r] = q; }
    }
    __syncthreads();
    #pragma unroll
    for (int r = 0; r < 4; ++r) {
        int lrow = lg*4 + r;
        float s = red[0][0][lrow] + red[0][1][lrow] + red[0][2][lrow] + red[0][3][lrow];
        float q = red[1][0][lrow] + red[1][1][lrow] + red[1][2][lrow] + red[1][3][lrow];
        float mean = s * (1.f / 256.f);
        float var  = q * (1.f / 256.f) - mean * mean;
        float inv  = rsqrtf(var + LN_EPS);
        long grow = rowbase + lrow;
        #pragma unroll
        for (int nt = 0; nt < 4; ++nt) {
            int col = w*64 + nt*16 + lr;
            float y = (acc[nt][r] - mean) * inv * g[col] + bb[col];
            if (MODE == 0) {
                ((__bf16*)out)[grow * 512 + 256 + col] = (__bf16)y;
            } else {
                ((float*)out)[grow * 256 + col] = xf[grow * 256 + col] + y;
            }
        }
    }
    if (MODE == 0) {   // copy xb rows -> cat left half
        int r = t >> 4, c0 = (t & 15) * 16;
        bf16x8 v0 = *(const bf16x8*)&xb[(long)(rowbase + r) * 256 + c0];
        bf16x8 v1 = *(const bf16x8*)&xb[(long)(rowbase + r) * 256 + c0 + 8];
        *(bf16x8*)&((__bf16*)out)[(long)(rowbase + r) * 512 + c0]     = v0;
        *(bf16x8*)&((__bf16*)out)[(long)(rowbase + r) * 512 + c0 + 8] = v1;
    }
}

// ---------------- split-KV flash attention partial ---------------------------------
// grid (32 qb, 4 h, 2*SPLIT); each block: 64 q x CHUNK kv, KVB=64 per iter
__global__ __launch_bounds__(256) void attn_part_kernel(
    const __bf16* __restrict__ q, const __bf16* __restrict__ kk,
    const __bf16* __restrict__ v, float* __restrict__ op, float* __restrict__ ml)
{
    __shared__ alignas(16) __bf16 QP[4 * 16 * 72];   // Qs (first 4096 elems) ∪ Ps
    __shared__ alignas(16) __bf16 Ks[64 * 64];       // linear, swizzled (stage64)
    __shared__ alignas(16) __bf16 Vt[64][72];        // transposed V, s-col XOR-swizzled

    const int t = threadIdx.x;
    const int qb = blockIdx.x * 64;
    const int h  = blockIdx.y;
    const int z  = blockIdx.z;
    const int b  = z >> 3, sp = z & 7;
    const int w = t >> 6, lane = t & 63;
    const int lr = lane & 15, lg = lane >> 4;
    const long row0 = (long)b * NN;

    __bf16 (*Ps)[16][72] = (__bf16 (*)[16][72])QP;

    // load Q tile (64 x 64) via gload_lds into QP (as Qs)
    stage64(q + (row0 + qb) * DD + h * HD, DD, QP, t);
    __syncthreads();
    bf16x8 qf[2];
    qf[0] = ldfrag_swz(QP, w*16 + lr, lg*8);
    qf[1] = ldfrag_swz(QP, w*16 + lr, 64 + lg*8);

    f32x4 acco[4] = {};
    float mrun[4], lrun[4];
    #pragma unroll
    for (int r = 0; r < 4; ++r) { mrun[r] = -INFINITY; lrun[r] = 0.f; }

    const int sr = t >> 2, scc = (t & 3) * 16;
    for (int sb = sp * CHUNK; sb < sp * CHUNK + CHUNK; sb += KVB) {
        __syncthreads();
        // stage K via gload_lds; V transposed via VGPR scatter (proven R10 path)
        stage64(kk + (row0 + sb) * DD + h * HD, DD, Ks, t);
        {
            const __bf16* vp = &v[(row0 + sb + sr) * DD + h * HD + scc];
            bf16x8 v0 = *(const bf16x8*)vp;
            bf16x8 v1 = *(const bf16x8*)(vp + 8);
            #pragma unroll
            for (int j = 0; j < 8; ++j) {
                int hd = scc + j;
                Vt[hd][sr ^ (4 * ((hd >> 3) & 7))] = v0[j];
                int hd2 = scc + 8 + j;
                Vt[hd2][sr ^ (4 * ((hd2 >> 3) & 7))] = v1[j];
            }
        }
        __syncthreads();

        // scores: Q @ K^T (16q x 64s per wave)
        f32x4 accs[4] = {};
        #pragma unroll
        for (int nt = 0; nt < 4; ++nt)
            #pragma unroll
            for (int ks = 0; ks < 2; ++ks) {
                bf16x8 kf = ldfrag_swz(Ks, nt*16 + lr, ks*64 + lg*8);
                accs[nt] = __builtin_amdgcn_mfma_f32_16x16x32_bf16(qf[ks], kf, accs[nt], 0, 0, 0);
            }

        // online softmax; lane holds rows 4*lg + r, cols {lr, lr+16, lr+32, lr+48}
        float sc[4];
        #pragma unroll
        for (int r = 0; r < 4; ++r) {
            float s0 = accs[0][r] * 0.125f, s1 = accs[1][r] * 0.125f;
            float s2 = accs[2][r] * 0.125f, s3 = accs[3][r] * 0.125f;
            float mx = fmaxf(fmaxf(s0, s1), fmaxf(s2, s3));
            #pragma unroll
            for (int m = 1; m < 16; m <<= 1) mx = fmaxf(mx, __shfl_xor(mx, m));
            float mnew = fmaxf(mrun[r], mx);
            float p0 = __expf(s0 - mnew), p1 = __expf(s1 - mnew);
            float p2 = __expf(s2 - mnew), p3 = __expf(s3 - mnew);
            float rs = (p0 + p1) + (p2 + p3);
            #pragma unroll
            for (int m = 1; m < 16; m <<= 1) rs += __shfl_xor(rs, m);
            sc[r] = __expf(mrun[r] - mnew);
            lrun[r] = lrun[r] * sc[r] + rs;
            mrun[r] = mnew;
            Ps[w][lg*4 + r][lr]      = (__bf16)p0;
            Ps[w][lg*4 + r][lr + 16] = (__bf16)p1;
            Ps[w][lg*4 + r][lr + 32] = (__bf16)p2;
            Ps[w][lg*4 + r][lr + 48] = (__bf16)p3;
        }
        asm volatile("s_waitcnt lgkmcnt(0)" ::: "memory");
        __builtin_amdgcn_sched_barrier(0);

        bf16x8 pf[2];
        pf[0] = ldfrag(&Ps[w][lr][4*lg]);
        pf[1] = ldfrag(&Ps[w][lr][32 + 4*lg]);

        // o += P @ V  (V via swizzled transposed LDS)
        #pragma unroll
        for (int nt = 0; nt < 4; ++nt) {
            #pragma unroll
            for (int r = 0; r < 4; ++r) acco[nt][r] *= sc[r];
            int d = nt*16 + lr;
            int xsw = 4 * ((d >> 3) & 7);
            const __bf16* vrow = &Vt[d][0];
            #pragma unroll
            for (int ks = 0; ks < 2; ++ks) {
                bf16x4 lo = *(const bf16x4*)&vrow[(ks*32 + 4*lg) ^ xsw];
                bf16x4 hi = *(const bf16x4*)&vrow[(ks*32 + 16 + 4*lg) ^ xsw];
                acco[nt] = __builtin_amdgcn_mfma_f32_16x16x32_bf16(pf[ks], make8(lo, hi), acco[nt], 0, 0, 0);
            }
        }
    }

    // write unnormalized partial O + (m, l)
    long pr = (long)(sp * 2 + b) * 2048 + qb + w*16 + lg*4;
    #pragma unroll
    for (int nt = 0; nt < 4; ++nt)
        #pragma unroll
        for (int r = 0; r < 4; ++r)
            op[(pr + r) * 256 + h * HD + nt*16 + lr] = acco[nt][r];
    if (lr == 0) {
        #pragma unroll
        for (int r = 0; r < 4; ++r) {
            long mi = ((long)(sp * 2 + b) * 4 + h) * 2048 + (qb + w*16 + lg*4 + r);
            *(float2*)&ml[mi * 2] = make_float2(mrun[r], lrun[r]);
        }
    }
}

// ---------------- combine SPLIT partials -> bf16 O ---------------------------------
__global__ __launch_bounds__(256) void attn_comb_kernel(
    const float* __restrict__ op, const float* __restrict__ ml, __bf16* __restrict__ o)
{
    int row = blockIdx.x;           // b*2048 + n
    int t = threadIdx.x;
    int b = row >> 11, n = row & 2047;
    int h = t >> 6;
    float m[SPLIT], l[SPLIT];
    #pragma unroll
    for (int sp = 0; sp < SPLIT; ++sp) {
        float2 v2 = *(const float2*)&ml[(((long)(sp*2 + b) * 4 + h) * 2048 + n) * 2];
        m[sp] = v2.x; l[sp] = v2.y;
    }
    float M = m[0];
    #pragma unroll
    for (int sp = 1; sp < SPLIT; ++sp) M = fmaxf(M, m[sp]);
    float L = 0.f, oa = 0.f;
    #pragma unroll
    for (int sp = 0; sp < SPLIT; ++sp) {
        float wgt = __expf(m[sp] - M);
        L  += l[sp] * wgt;
        oa += op[((long)(sp*2 + b) * 2048 + n) * 256 + t] * wgt;
    }
    o[(long)row * 256 + t] = (__bf16)(oa / L);
}

extern "C" void kernel_launch(void* const* d_in, const int* in_sizes, int n_in,
                              void* d_out, int out_size, void* d_ws, size_t ws_size,
                              hipStream_t stream)
{
    const float* x   = (const float*)d_in[0];
    const float* src = (const float*)d_in[1];
    const float* xpe = (const float*)d_in[2];
    const float* spe = (const float*)d_in[3];
    const float* Wq  = (const float*)d_in[4];
    const float* Wk  = (const float*)d_in[5];
    const float* Wv  = (const float*)d_in[6];
    const float* Wm  = (const float*)d_in[7];
    const float* W1  = (const float*)d_in[8];
    const float* W2  = (const float*)d_in[9];
    const float* g1  = (const float*)d_in[10];
    const float* b1  = (const float*)d_in[11];
    const float* g2  = (const float*)d_in[12];
    const float* b2  = (const float*)d_in[13];

    char* ws = (char*)d_ws;
    size_t off = 0;
    auto alloc = [&](size_t bytes) -> void* {
        void* p = ws + off; off += (bytes + 255) & ~(size_t)255; return p;
    };
    __bf16* Wqt  = (__bf16*)alloc(256 * 256 * 2);
    __bf16* Wkvt = (__bf16*)alloc(512 * 256 * 2);
    __bf16* Wmt  = (__bf16*)alloc(256 * 256 * 2);
    __bf16* W1t  = (__bf16*)alloc(512 * 512 * 2);
    __bf16* W2t  = (__bf16*)alloc(256 * 512 * 2);
    __bf16* xb   = (__bf16*)alloc((size_t)4096 * 256 * 2);
    __bf16* srcb = (__bf16*)alloc((size_t)4096 * 256 * 2);
    __bf16* qws  = (__bf16*)alloc((size_t)4096 * 256 * 2);
    __bf16* kws  = (__bf16*)alloc((size_t)4096 * 256 * 2);
    __bf16* vws  = (__bf16*)alloc((size_t)4096 * 256 * 2);
    __bf16* ows  = (__bf16*)alloc((size_t)4096 * 256 * 2);
    float*  op   = (float*) alloc((size_t)SPLIT * 2 * 2048 * 256 * 4);   // 32 MB
    float*  ml   = (float*) alloc((size_t)SPLIT * 2 * 4 * 2048 * 2 * 4); // 1 MB
    __bf16* cat  = (__bf16*)alloc((size_t)4096 * 512 * 2);
    __bf16* hws  = (__bf16*)alloc((size_t)4096 * 512 * 2);

    wtall_kernel<<<3584, 256, 0, stream>>>(Wq, Wk, Wv, Wm, W1, W2, x, src,
                                           Wqt, Wkvt, Wmt, W1t, W2t, xb, srcb);

    gemm2_kernel<5><<<dim3(12, 64), 256, 0, stream>>>(
        xb, srcb, Wqt, Wkvt, qws, kws, vws, xpe, spe, 4096, 256, 256);

    attn_part_kernel<<<dim3(32, 4, 2 * SPLIT), 256, 0, stream>>>(qws, kws, vws, op, ml);
    attn_comb_kernel<<<4096, 256, 0, stream>>>(op, ml, ows);

    gemm_ln_kernel<0><<<256, 256, 0, stream>>>(ows, Wmt, xb, nullptr, g1, b1, cat, 256);
    gemm2_kernel<3><<<dim3(8, 64), 256, 0, stream>>>(
        cat, nullptr, W1t, nullptr, hws, nullptr, nullptr, nullptr, nullptr, 4096, 512, 512);
    gemm_ln_kernel<1><<<256, 256, 0, stream>>>(hws, W2t, nullptr, x, g2, b2, d_out, 512);
}